// Round 15
// baseline (1086.678 us; speedup 1.0000x reference)
//
#include <hip/hip_runtime.h>
#include <hip/hip_bf16.h>

#define N_NODES 50000
#define N_EDGES 800000
#define D 128
#define NLAYERS 4
#define N_GRAPHS 512
#define N_CLASSES 10
#define BN_EPS 1e-5f
#define SCAN_BLOCKS ((N_NODES + 1023) / 1024)
#define NPART 64   // BN-stat partial buffers
#define NCHUNK 8   // feature chunks == XCD count; chunk = blockIdx & 7
#define CHUNKW 16  // 16 cols * 4B = 64B per row per chunk; 3.2MB/chunk < 4MiB XCD L2

// ---------------- CSR build ----------------
__global__ void k_hist(const int* __restrict__ ei, int* __restrict__ counts) {
    int e = blockIdx.x * blockDim.x + threadIdx.x;
    if (e < N_EDGES) atomicAdd(&counts[ei[N_EDGES + e]], 1);
}

// per-1024-block inclusive scan; also deg_inv = rsqrt(count+1)
__global__ __launch_bounds__(1024) void k_scan1(const int* __restrict__ counts,
                                                int* __restrict__ offsets,
                                                float* __restrict__ deg_inv,
                                                int* __restrict__ bsum) {
    __shared__ int wsum[16];
    int tid = threadIdx.x, lane = tid & 63, wid = tid >> 6;
    int i = blockIdx.x * 1024 + tid;
    int v = (i < N_NODES) ? counts[i] : 0;
    if (i < N_NODES) deg_inv[i] = rsqrtf((float)v + 1.0f);
    int x = v;
    #pragma unroll
    for (int off = 1; off < 64; off <<= 1) {
        int y = __shfl_up(x, off, 64);
        if (lane >= off) x += y;
    }
    if (lane == 63) wsum[wid] = x;
    __syncthreads();
    if (wid == 0 && lane < 16) {
        int w = wsum[lane];
        #pragma unroll
        for (int off = 1; off < 16; off <<= 1) {
            int y = __shfl_up(w, off, 16);
            if (lane >= off) w += y;
        }
        wsum[lane] = w;
    }
    __syncthreads();
    int wbase = (wid > 0) ? wsum[wid - 1] : 0;
    int incl = x + wbase;
    if (i < N_NODES) offsets[i + 1] = incl;
    if (tid == 1023) bsum[blockIdx.x] = incl;
}

// add block-prefix; block 0 thread 0 writes offsets[0]
__global__ __launch_bounds__(1024) void k_scan2(int* __restrict__ offsets,
                                                const int* __restrict__ bsum) {
    __shared__ int s_pre;
    int b = blockIdx.x, tid = threadIdx.x;
    if (tid == 0) {
        int p = 0;
        for (int j = 0; j < b; j++) p += bsum[j];
        s_pre = p;
        if (b == 0) offsets[0] = 0;
    }
    __syncthreads();
    int i = b * 1024 + tid;
    if (i < N_NODES) offsets[i + 1] += s_pre;
}

__global__ void k_scatter(const int* __restrict__ ei, const int* __restrict__ offsets,
                          int* __restrict__ cursor, const float* __restrict__ deg_inv,
                          int2* __restrict__ csr) {
    int e = blockIdx.x * blockDim.x + threadIdx.x;
    if (e >= N_EDGES) return;
    int s = ei[e];
    int d = ei[N_EDGES + e];
    int pos = offsets[d] + atomicAdd(&cursor[d], 1);
    csr[pos] = make_int2(s, __float_as_int(deg_inv[s] * deg_inv[d]));
}

// ---------------- GEMM: Hc = f(X) @ W  (chunk-major output) ----------------
// gstats = [NPART][2][D] partials from previous k_agg (or null for layer 0)
#define GEMM_BM 64
__global__ __launch_bounds__(256) void k_gemm(const float* __restrict__ X,
                                              const float* __restrict__ Wl,
                                              float* __restrict__ Hc,
                                              const float* __restrict__ gstats,
                                              const float* __restrict__ gamma,
                                              const float* __restrict__ beta,
                                              int do_bn_relu) {
    __shared__ float xs[GEMM_BM][D];   // 32 KB
    __shared__ float s_sc[D], s_sh[D];
    int tid = threadIdx.x;
    if (tid < D) {
        if (do_bn_relu) {
            float s = 0.f, q = 0.f;
            #pragma unroll 8
            for (int p = 0; p < NPART; p++) {
                s += gstats[p * 2 * D + tid];
                q += gstats[p * 2 * D + D + tid];
            }
            const float invN = 1.0f / (float)N_NODES;
            float mu = s * invN;
            float var = q * invN - mu * mu;
            float sc = gamma[tid] * rsqrtf(var + BN_EPS);
            s_sc[tid] = sc;
            s_sh[tid] = beta[tid] - mu * sc;
        } else {
            s_sc[tid] = 1.0f;
            s_sh[tid] = 0.0f;
        }
    }
    __syncthreads();
    int row0 = blockIdx.x * GEMM_BM;
    #pragma unroll
    for (int j = 0; j < 8; j++) {
        int idx = tid + j * 256;       // float4 index (2048 total)
        int r = idx >> 5;
        int c4 = (idx & 31) * 4;
        float4 v;
        int gr = row0 + r;
        if (gr < N_NODES) v = *(const float4*)&X[(long)gr * D + c4];
        else v = make_float4(0.f, 0.f, 0.f, 0.f);
        if (do_bn_relu) {
            v.x = fmaxf(v.x * s_sc[c4 + 0] + s_sh[c4 + 0], 0.f);
            v.y = fmaxf(v.y * s_sc[c4 + 1] + s_sh[c4 + 1], 0.f);
            v.z = fmaxf(v.z * s_sc[c4 + 2] + s_sh[c4 + 2], 0.f);
            v.w = fmaxf(v.w * s_sc[c4 + 3] + s_sh[c4 + 3], 0.f);
        }
        *(float4*)&xs[r][c4] = v;
    }
    __syncthreads();
    int tc = tid & 31, tr = tid >> 5;
    int r0 = tr * 8, c0 = tc * 4;
    float acc[8][4] = {};
    #pragma unroll 4
    for (int k = 0; k < D; k++) {
        float4 w = *(const float4*)&Wl[k * D + c0];
        #pragma unroll
        for (int i = 0; i < 8; i++) {
            float xv = xs[r0 + i][k];
            acc[i][0] += xv * w.x;
            acc[i][1] += xv * w.y;
            acc[i][2] += xv * w.z;
            acc[i][3] += xv * w.w;
        }
    }
    // chunk-major write: Hc[chunk][node][16]
    int chunk = c0 >> 4;
    int within = c0 & 15;
    #pragma unroll
    for (int i = 0; i < 8; i++) {
        int gr = row0 + r0 + i;
        if (gr < N_NODES) {
            float4 o = make_float4(acc[i][0], acc[i][1], acc[i][2], acc[i][3]);
            *(float4*)&Hc[(size_t)chunk * N_NODES * CHUNKW + (size_t)gr * CHUNKW + within] = o;
        }
    }
}

// ---------------- XCD-chunked aggregation + bias + BN-stat partials ----------
// grid = (N_NODES/16) * 8; chunk = blockIdx&7 -> lands on XCD (blockIdx%8) so
// each XCD's L2 holds its 3.2MB chunk of Hc. lane = (edge-slot 0-3, col 0-15).
#define AGGC_NPW 4
#define AGGC_WAVES 4
#define AGGC_NPB (AGGC_NPW * AGGC_WAVES)   // 16 nodes per block
__global__ __launch_bounds__(256) void k_agg(const float* __restrict__ Hc,
                                             const float* __restrict__ deg_inv,
                                             const int* __restrict__ offsets,
                                             const int2* __restrict__ csr,
                                             const float* __restrict__ bias,
                                             float* __restrict__ Xout,
                                             float* __restrict__ gstats) { // [NPART][2][D]
    __shared__ float s_sum[CHUNKW], s_sq[CHUNKW];
    int tid = threadIdx.x, lane = tid & 63, wid = tid >> 6;
    int bid = blockIdx.x;
    int chunk = bid & (NCHUNK - 1);
    int grp = bid >> 3;
    if (tid < CHUNKW) { s_sum[tid] = 0.f; s_sq[tid] = 0.f; }
    __syncthreads();
    const float* Hbase = Hc + (size_t)chunk * N_NODES * CHUNKW;
    int col = lane & 15;
    int slot = lane >> 4;
    float b = bias[chunk * CHUNKW + col];
    float ps = 0.f, pq = 0.f;
    int n0 = grp * AGGC_NPB + wid * AGGC_NPW;   // exact: 3125*16 = 50000
    for (int t = 0; t < AGGC_NPW; t++) {
        int n = n0 + t;
        float a = 0.f;
        int e = offsets[n], e1 = offsets[n + 1];
        // 2 batches of 4 edges in flight; csr nontemporal (don't evict chunk)
        for (; e + 8 <= e1; e += 8) {
            long long v0 = __builtin_nontemporal_load((const long long*)&csr[e + slot]);
            long long v1 = __builtin_nontemporal_load((const long long*)&csr[e + 4 + slot]);
            int src0 = (int)v0; float w0 = __int_as_float((int)(v0 >> 32));
            int src1 = (int)v1; float w1 = __int_as_float((int)(v1 >> 32));
            float h0 = Hbase[(size_t)src0 * CHUNKW + col];
            float h1 = Hbase[(size_t)src1 * CHUNKW + col];
            a += h0 * w0 + h1 * w1;
        }
        for (; e < e1; e += 4) {
            int ee = e + slot;
            if (ee < e1) {
                long long v = __builtin_nontemporal_load((const long long*)&csr[ee]);
                int src = (int)v; float w = __int_as_float((int)(v >> 32));
                a += Hbase[(size_t)src * CHUNKW + col] * w;
            }
        }
        a += __shfl_xor(a, 16, 64);
        a += __shfl_xor(a, 32, 64);
        if (slot == 0) {
            float di = deg_inv[n];
            float r = a + Hbase[(size_t)n * CHUNKW + col] * (di * di) + b;
            __builtin_nontemporal_store(r, &Xout[(size_t)n * D + chunk * CHUNKW + col]);
            ps += r;
            pq += r * r;
        }
    }
    if (slot == 0) {
        atomicAdd(&s_sum[col], ps);
        atomicAdd(&s_sq[col], pq);
    }
    __syncthreads();
    if (tid < CHUNKW) {
        int part = grp & (NPART - 1);
        float* gp = gstats + (size_t)part * 2 * D;
        atomicAdd(&gp[chunk * CHUNKW + tid], s_sum[tid]);
        atomicAdd(&gp[D + chunk * CHUNKW + tid], s_sq[tid]);
    }
}

// ---------------- Fused final BN+ReLU + mean-pool + classifier ----------------
__global__ __launch_bounds__(256) void k_poolcls(const float* __restrict__ X,
                                                 const int* __restrict__ batch,
                                                 const float* __restrict__ gstats, // [NPART][2][D]
                                                 const float* __restrict__ gamma,
                                                 const float* __restrict__ beta,
                                                 const float* __restrict__ Wc,
                                                 const float* __restrict__ bc,
                                                 float* __restrict__ out) {
    __shared__ float s_pool[D];
    __shared__ float s_sc[D], s_sh[D];
    __shared__ int s_lo, s_hi;
    int g = blockIdx.x, tid = threadIdx.x;
    if (tid == 0) {
        int lo = 0, hi = N_NODES;
        while (lo < hi) { int m = (lo + hi) >> 1; if (batch[m] < g) lo = m + 1; else hi = m; }
        s_lo = lo;
        hi = N_NODES;
        while (lo < hi) { int m = (lo + hi) >> 1; if (batch[m] < g + 1) lo = m + 1; else hi = m; }
        s_hi = lo;
    }
    if (tid < D) {
        float s = 0.f, q = 0.f;
        #pragma unroll 8
        for (int p = 0; p < NPART; p++) {
            s += gstats[p * 2 * D + tid];
            q += gstats[p * 2 * D + D + tid];
        }
        const float invN = 1.0f / (float)N_NODES;
        float mu = s * invN;
        float var = q * invN - mu * mu;
        float sc = gamma[tid] * rsqrtf(var + BN_EPS);
        s_sc[tid] = sc;
        s_sh[tid] = beta[tid] - mu * sc;
        s_pool[tid] = 0.f;
    }
    __syncthreads();
    int lo = s_lo, hi = s_hi;
    int c4 = (tid & 31) * 4, q = tid >> 5;   // 8 row-groups in flight
    float sc[4], sh[4];
    #pragma unroll
    for (int j = 0; j < 4; j++) { sc[j] = s_sc[c4 + j]; sh[j] = s_sh[c4 + j]; }
    float acc[4] = {0.f, 0.f, 0.f, 0.f};
    for (int n = lo + q; n < hi; n += 8) {
        float4 v = *(const float4*)&X[(long)n * D + c4];
        acc[0] += fmaxf(v.x * sc[0] + sh[0], 0.f);
        acc[1] += fmaxf(v.y * sc[1] + sh[1], 0.f);
        acc[2] += fmaxf(v.z * sc[2] + sh[2], 0.f);
        acc[3] += fmaxf(v.w * sc[3] + sh[3], 0.f);
    }
    #pragma unroll
    for (int j = 0; j < 4; j++) atomicAdd(&s_pool[c4 + j], acc[j]);
    __syncthreads();
    if (tid < N_CLASSES) {
        float cnt = fmaxf((float)(hi - lo), 1.0f);
        float r = 0.f;
        #pragma unroll 16
        for (int k = 0; k < D; k++) r += s_pool[k] * Wc[k * N_CLASSES + tid];
        out[(long)g * N_CLASSES + tid] = r / cnt + bc[tid];
    }
}

// ---------------- launch ----------------
extern "C" void kernel_launch(void* const* d_in, const int* in_sizes, int n_in,
                              void* d_out, int out_size, void* d_ws, size_t ws_size,
                              hipStream_t stream) {
    const float* x     = (const float*)d_in[0];
    const float* W     = (const float*)d_in[1];   // [4,128,128]
    const float* b     = (const float*)d_in[2];   // [4,128]
    const float* gamma = (const float*)d_in[3];
    const float* beta  = (const float*)d_in[4];
    const float* Wc    = (const float*)d_in[5];
    const float* bc    = (const float*)d_in[6];
    const int*   ei    = (const int*)d_in[7];     // [2, E]
    const int*   batch = (const int*)d_in[8];
    float* out = (float*)d_out;

    char* ws = (char*)d_ws;
    size_t off = 0;
    auto alloc = [&](size_t bytes) {
        void* p = ws + off;
        off += (bytes + 255) & ~(size_t)255;
        return p;
    };
    float* cur_x    = (float*)alloc((size_t)N_NODES * D * 4);
    float* h        = (float*)alloc((size_t)N_NODES * D * 4);   // chunk-major Hc
    float* deg_inv  = (float*)alloc(N_NODES * 4);
    int*   offsets  = (int*)alloc((N_NODES + 1) * 4);
    int2*  csr      = (int2*)alloc((size_t)N_EDGES * 8);
    int*   bsum     = (int*)alloc(SCAN_BLOCKS * 4);
    // --- zeroed region (one memset): counts | cursor | gstats[4][NPART][2][128] ---
    size_t zero_begin = off;
    int*   counts   = (int*)alloc(N_NODES * 4);
    int*   cursor   = (int*)alloc(N_NODES * 4);
    float* gstats   = (float*)alloc((size_t)NLAYERS * NPART * 2 * D * 4);
    size_t zero_end = off;

    hipMemsetAsync(ws + zero_begin, 0, zero_end - zero_begin, stream);

    k_hist<<<(N_EDGES + 255) / 256, 256, 0, stream>>>(ei, counts);
    k_scan1<<<SCAN_BLOCKS, 1024, 0, stream>>>(counts, offsets, deg_inv, bsum);
    k_scan2<<<SCAN_BLOCKS, 1024, 0, stream>>>(offsets, bsum);
    k_scatter<<<(N_EDGES + 255) / 256, 256, 0, stream>>>(ei, offsets, cursor, deg_inv, csr);

    const int gemm_grid = (N_NODES + GEMM_BM - 1) / GEMM_BM;
    const int agg_grid = (N_NODES / AGGC_NPB) * NCHUNK;   // 3125 * 8 = 25000
    const size_t lstat = (size_t)NPART * 2 * D;
    for (int l = 0; l < NLAYERS; l++) {
        const float* Xin = (l == 0) ? x : cur_x;
        const float* st  = (l == 0) ? nullptr : gstats + (size_t)(l - 1) * lstat;
        const float* gm  = gamma + (size_t)((l == 0) ? 0 : l - 1) * D;
        const float* bt  = beta + (size_t)((l == 0) ? 0 : l - 1) * D;
        k_gemm<<<gemm_grid, 256, 0, stream>>>(Xin, W + (size_t)l * D * D, h,
                                              st, gm, bt, (l == 0) ? 0 : 1);
        k_agg<<<agg_grid, 256, 0, stream>>>(h, deg_inv, offsets, csr,
                                            b + (size_t)l * D, cur_x,
                                            gstats + (size_t)l * lstat);
    }

    k_poolcls<<<N_GRAPHS, 256, 0, stream>>>(cur_x, batch,
                                            gstats + (size_t)(NLAYERS - 1) * lstat,
                                            gamma + (size_t)(NLAYERS - 1) * D,
                                            beta + (size_t)(NLAYERS - 1) * D,
                                            Wc, bc, out);
}